// Round 2
// baseline (475.725 us; speedup 1.0000x reference)
//
#include <hip/hip_runtime.h>
#include <cstdint>
#include <cstddef>

typedef unsigned short u16;
typedef unsigned int uint;
typedef __bf16 bf16x8 __attribute__((ext_vector_type(8)));
typedef float f32x4 __attribute__((ext_vector_type(4)));

#define BATCH 2
#define SEQ 2048
#define DIM 1024
#define NH 16
#define DH 64
#define FFD 4096
#define MROWS 4096            // BATCH*SEQ
#define PER_BATCH 2097152     // SEQ*DIM

__device__ __forceinline__ u16 f2b(float f) {
  uint u = __builtin_bit_cast(uint, f);
  u += 0x7FFFu + ((u >> 16) & 1u);   // RNE
  return (u16)(u >> 16);
}

// ---------------------------------------------------------------- elementwise
__global__ __launch_bounds__(256) void cvt_kernel(const float* __restrict__ src,
                                                  u16* __restrict__ dst, int n) {
  int i = (blockIdx.x * 256 + threadIdx.x) * 8;
  if (i >= n) return;
  float4 a = *(const float4*)(src + i);
  float4 b = *(const float4*)(src + i + 4);
  uint4 o;
  o.x = f2b(a.x) | ((uint)f2b(a.y) << 16);
  o.y = f2b(a.z) | ((uint)f2b(a.w) << 16);
  o.z = f2b(b.x) | ((uint)f2b(b.y) << 16);
  o.w = f2b(b.z) | ((uint)f2b(b.w) << 16);
  *(uint4*)(dst + i) = o;
}

__global__ __launch_bounds__(256) void reduce_stats_kernel(const float* __restrict__ x,
                                                           float* __restrict__ stats) {
  int b = blockIdx.y;
  const float* p = x + (size_t)b * PER_BATCH;
  float s = 0.f, ss = 0.f;
  int stride = gridDim.x * 256 * 4;
  for (int i = (blockIdx.x * 256 + threadIdx.x) * 4; i < PER_BATCH; i += stride) {
    float4 v = *(const float4*)(p + i);
    s  += (v.x + v.y) + (v.z + v.w);
    ss += (v.x * v.x + v.y * v.y) + (v.z * v.z + v.w * v.w);
  }
#pragma unroll
  for (int m = 32; m; m >>= 1) { s += __shfl_xor(s, m); ss += __shfl_xor(ss, m); }
  __shared__ float red[16];
  int w = threadIdx.x >> 6;
  if ((threadIdx.x & 63) == 0) { red[w] = s; red[8 + w] = ss; }
  __syncthreads();
  if (threadIdx.x == 0) {
    atomicAdd(&stats[b * 2],     red[0] + red[1] + red[2] + red[3]);
    atomicAdd(&stats[b * 2 + 1], red[8] + red[9] + red[10] + red[11]);
  }
}

__global__ __launch_bounds__(256) void ln_apply_kernel(const float* __restrict__ xin,
                                                       const float* __restrict__ stats,
                                                       u16* __restrict__ out) {
  int i = (blockIdx.x * 256 + threadIdx.x) * 4;
  int b = i >> 21;   // i / PER_BATCH
  const float inv = 1.f / (float)PER_BATCH;
  float mu = stats[b * 2] * inv;
  float var = stats[b * 2 + 1] * inv - mu * mu;
  float rs = rsqrtf(var + 1e-5f);
  float4 v = *(const float4*)(xin + i);
  uint r0 = f2b((v.x - mu) * rs) | ((uint)f2b((v.y - mu) * rs) << 16);
  uint r1 = f2b((v.z - mu) * rs) | ((uint)f2b((v.w - mu) * rs) << 16);
  *(uint2*)(out + i) = make_uint2(r0, r1);
}

// ---------------------------------------------------------------- GEMM (C = A * B^T)
// A: MxK bf16 row-major; Bm: NxK bf16 row-major; bias: per-col fp32.
// RELU: relu(acc+bias); RESID: add fp32 resid[row*N+col]; OUTBF: write bf16 else fp32.
template <int RELU, int RESID, int OUTBF>
__device__ __forceinline__ void gemm_bt_body(const u16* __restrict__ A,
                                             const u16* __restrict__ Bm,
                                             const float* __restrict__ bias,
                                             const float* __restrict__ resid,
                                             void* __restrict__ Cout,
                                             int M, int N, int K,
                                             int m0, int n0) {
  __shared__ u16 As[128 * 72];
  __shared__ u16 Bs[128 * 72];
  const int tid = threadIdx.x;
  const int lane = tid & 63, w = tid >> 6;
  const int wr = w >> 1, wc = w & 1;
  const int ln = lane & 15, qd = lane >> 4;

  f32x4 acc[4][4] = {};

  const int arow = tid >> 3;        // 0..31
  const int acol = (tid & 7) * 8;   // 0..56
  const u16* Aptr = A + (size_t)(m0 + arow) * K + acol;
  const u16* Bptr = Bm + (size_t)(n0 + arow) * K + acol;

  for (int k0 = 0; k0 < K; k0 += 64) {
    __syncthreads();
#pragma unroll
    for (int r = 0; r < 4; ++r) {
      float4 av = *(const float4*)(Aptr + (size_t)(r * 32) * K + k0);
      float4 bv = *(const float4*)(Bptr + (size_t)(r * 32) * K + k0);
      *(float4*)&As[(arow + r * 32) * 72 + acol] = av;
      *(float4*)&Bs[(arow + r * 32) * 72 + acol] = bv;
    }
    __syncthreads();
#pragma unroll
    for (int kk = 0; kk < 2; ++kk) {
      bf16x8 af[4], bf[4];
#pragma unroll
      for (int t = 0; t < 4; ++t) {
        af[t] = *(const bf16x8*)&As[(wr * 64 + t * 16 + ln) * 72 + kk * 32 + qd * 8];
        bf[t] = *(const bf16x8*)&Bs[(wc * 64 + t * 16 + ln) * 72 + kk * 32 + qd * 8];
      }
#pragma unroll
      for (int i = 0; i < 4; ++i)
#pragma unroll
        for (int j = 0; j < 4; ++j)
          acc[i][j] = __builtin_amdgcn_mfma_f32_16x16x32_bf16(af[i], bf[j], acc[i][j], 0, 0, 0);
    }
  }

#pragma unroll
  for (int i = 0; i < 4; ++i) {
    int row = m0 + wr * 64 + i * 16 + qd * 4;
#pragma unroll
    for (int j = 0; j < 4; ++j) {
      int col = n0 + wc * 64 + j * 16 + ln;
      float bv = bias[col];
#pragma unroll
      for (int r = 0; r < 4; ++r) {
        float v = acc[i][j][r] + bv;
        if (RELU) v = fmaxf(v, 0.f);
        size_t off = (size_t)(row + r) * N + col;
        if (RESID) v += resid[off];
        if (OUTBF) ((u16*)Cout)[off] = f2b(v);
        else       ((float*)Cout)[off] = v;
      }
    }
  }
}

template <int RELU, int RESID, int OUTBF>
__global__ __launch_bounds__(256) void gemm_bt_kernel(const u16* __restrict__ A,
                                                      const u16* __restrict__ Bm,
                                                      const float* __restrict__ bias,
                                                      const float* __restrict__ resid,
                                                      void* __restrict__ Cout,
                                                      int M, int N, int K) {
  gemm_bt_body<RELU, RESID, OUTBF>(A, Bm, bias, resid, Cout, M, N, K,
                                   blockIdx.y * 128, blockIdx.x * 128);
}

// fused QKV: blockIdx.z selects which of the three projections
__global__ __launch_bounds__(256) void gemm_qkv_kernel(const u16* __restrict__ A,
                                                       const u16* B0, const u16* B1, const u16* B2,
                                                       const float* c0, const float* c1, const float* c2,
                                                       u16* o0, u16* o1, u16* o2) {
  int z = blockIdx.z;
  const u16* Bm = (z == 0) ? B0 : (z == 1) ? B1 : B2;
  const float* bias = (z == 0) ? c0 : (z == 1) ? c1 : c2;
  u16* Cout = (z == 0) ? o0 : (z == 1) ? o1 : o2;
  gemm_bt_body<0, 0, 1>(A, Bm, bias, nullptr, Cout, MROWS, DIM, DIM,
                        blockIdx.y * 128, blockIdx.x * 128);
}

// ---------------------------------------------------------------- flash attention
// Q,K,V: (MROWS x DIM) bf16; per (b,head): rows b*SEQ+l, cols head*64+d.
// Block = (q-tile of 128 rows, head, batch); 4 waves, each owns 32 q rows.
__global__ __launch_bounds__(256) void attn_kernel(const u16* __restrict__ Q,
                                                   const u16* __restrict__ Km,
                                                   const u16* __restrict__ Vm,
                                                   u16* __restrict__ O) {
  __shared__ u16 Ks[128 * 72];        // K-tile (row = k-pos, col = Dh), pad 72
  __shared__ u16 Vt[64 * 136];        // V^T tile (row = Dh, col = k-pos), pad 136
  __shared__ u16 Ps[4 * 32 * 136];    // per-wave P chunk (32 x 128), pad 136

  const int tid = threadIdx.x, lane = tid & 63, w = tid >> 6;
  const int ln = lane & 15, qd = lane >> 4;
  const int qi = blockIdx.x, head = blockIdx.y, b = blockIdx.z;
  const int wq0 = b * SEQ + qi * 128 + w * 32;   // wave's first global q row
  const int hcol = head * DH;

  // Q fragments (held in registers for whole kernel)
  bf16x8 qf[2][2];
#pragma unroll
  for (int ti = 0; ti < 2; ++ti)
#pragma unroll
    for (int kk = 0; kk < 2; ++kk)
      qf[ti][kk] = *(const bf16x8*)&Q[(size_t)(wq0 + ti * 16 + ln) * DIM + hcol + kk * 32 + qd * 8];

  f32x4 accO[2][4] = {};
  float mrow[2][4], lrow[2][4];
#pragma unroll
  for (int ti = 0; ti < 2; ++ti)
#pragma unroll
    for (int r = 0; r < 4; ++r) { mrow[ti][r] = -1e30f; lrow[ti][r] = 0.f; }

  const int srow = tid >> 3;          // 0..31
  const int scol = (tid & 7) * 8;     // 0..56
  u16* Pw = &Ps[w * 32 * 136];

  for (int kt = 0; kt < SEQ; kt += 128) {
    __syncthreads();
#pragma unroll
    for (int r4 = 0; r4 < 4; ++r4) {
      int krow = kt + r4 * 32 + srow;
      float4 kv = *(const float4*)&Km[(size_t)(b * SEQ + krow) * DIM + hcol + scol];
      *(float4*)&Ks[(r4 * 32 + srow) * 72 + scol] = kv;
      union { float4 f; u16 u[8]; } vv;
      vv.f = *(const float4*)&Vm[(size_t)(b * SEQ + krow) * DIM + hcol + scol];
#pragma unroll
      for (int e = 0; e < 8; ++e)
        Vt[(scol + e) * 136 + r4 * 32 + srow] = vv.u[e];
    }
    __syncthreads();

    // S = Q K^T  (wave: 32 x 128)
    f32x4 sacc[2][8] = {};
#pragma unroll
    for (int kk = 0; kk < 2; ++kk) {
      bf16x8 kf[8];
#pragma unroll
      for (int tj = 0; tj < 8; ++tj)
        kf[tj] = *(const bf16x8*)&Ks[(tj * 16 + ln) * 72 + kk * 32 + qd * 8];
#pragma unroll
      for (int ti = 0; ti < 2; ++ti)
#pragma unroll
        for (int tj = 0; tj < 8; ++tj)
          sacc[ti][tj] = __builtin_amdgcn_mfma_f32_16x16x32_bf16(qf[ti][kk], kf[tj], sacc[ti][tj], 0, 0, 0);
    }
#pragma unroll
    for (int ti = 0; ti < 2; ++ti)
#pragma unroll
      for (int tj = 0; tj < 8; ++tj)
        sacc[ti][tj] *= 0.25f;   // faithful source bug: scale = 1/sqrt(H)

    // online softmax
    float mt[2][4];
#pragma unroll
    for (int ti = 0; ti < 2; ++ti)
#pragma unroll
      for (int r = 0; r < 4; ++r) {
        float m = sacc[ti][0][r];
#pragma unroll
        for (int tj = 1; tj < 8; ++tj) m = fmaxf(m, sacc[ti][tj][r]);
        mt[ti][r] = m;
      }
#pragma unroll
    for (int ti = 0; ti < 2; ++ti)
#pragma unroll
      for (int r = 0; r < 4; ++r) {
#pragma unroll
        for (int msk = 8; msk; msk >>= 1) mt[ti][r] = fmaxf(mt[ti][r], __shfl_xor(mt[ti][r], msk));
        float mn = fmaxf(mrow[ti][r], mt[ti][r]);
        float alpha = __expf(mrow[ti][r] - mn);
        mrow[ti][r] = mn;
        lrow[ti][r] *= alpha;
#pragma unroll
        for (int tjv = 0; tjv < 4; ++tjv) accO[ti][tjv][r] *= alpha;
      }

    float rs[2][4] = {};
#pragma unroll
    for (int ti = 0; ti < 2; ++ti)
#pragma unroll
      for (int tj = 0; tj < 8; ++tj)
#pragma unroll
        for (int r = 0; r < 4; ++r) {
          float p = __expf(sacc[ti][tj][r] - mrow[ti][r]);
          rs[ti][r] += p;
          Pw[(ti * 16 + qd * 4 + r) * 136 + tj * 16 + ln] = f2b(p);
        }
#pragma unroll
    for (int ti = 0; ti < 2; ++ti)
#pragma unroll
      for (int r = 0; r < 4; ++r) {
#pragma unroll
        for (int msk = 8; msk; msk >>= 1) rs[ti][r] += __shfl_xor(rs[ti][r], msk);
        lrow[ti][r] += rs[ti][r];
      }

    // O += P V  (P: 32x128 A-layout from LDS; V^T gives contiguous b-frags)
#pragma unroll
    for (int kk = 0; kk < 4; ++kk) {
      bf16x8 pf[2], vf[4];
#pragma unroll
      for (int ti = 0; ti < 2; ++ti)
        pf[ti] = *(const bf16x8*)&Pw[(ti * 16 + ln) * 136 + kk * 32 + qd * 8];
#pragma unroll
      for (int tjv = 0; tjv < 4; ++tjv)
        vf[tjv] = *(const bf16x8*)&Vt[(tjv * 16 + ln) * 136 + kk * 32 + qd * 8];
#pragma unroll
      for (int ti = 0; ti < 2; ++ti)
#pragma unroll
        for (int tjv = 0; tjv < 4; ++tjv)
          accO[ti][tjv] = __builtin_amdgcn_mfma_f32_16x16x32_bf16(pf[ti], vf[tjv], accO[ti][tjv], 0, 0, 0);
    }
  }

#pragma unroll
  for (int ti = 0; ti < 2; ++ti)
#pragma unroll
    for (int r = 0; r < 4; ++r) {
      float inv = 1.f / lrow[ti][r];
#pragma unroll
      for (int tjv = 0; tjv < 4; ++tjv)
        O[(size_t)(wq0 + ti * 16 + qd * 4 + r) * DIM + hcol + tjv * 16 + ln] =
            f2b(accO[ti][tjv][r] * inv);
    }
}

// ---------------------------------------------------------------- launch
extern "C" void kernel_launch(void* const* d_in, const int* in_sizes, int n_in,
                              void* d_out, int out_size, void* d_ws, size_t ws_size,
                              hipStream_t stream) {
  const float* x  = (const float*)d_in[0];
  const float* wq = (const float*)d_in[1];
  const float* bq = (const float*)d_in[2];
  const float* wk = (const float*)d_in[3];
  const float* bk = (const float*)d_in[4];
  const float* wv = (const float*)d_in[5];
  const float* bv = (const float*)d_in[6];
  const float* wo = (const float*)d_in[7];
  const float* bo = (const float*)d_in[8];
  const float* w1 = (const float*)d_in[9];
  const float* b1 = (const float*)d_in[10];
  const float* w2 = (const float*)d_in[11];
  const float* b2 = (const float*)d_in[12];
  float* out = (float*)d_out;
  char* ws = (char*)d_ws;

  const size_t MB = 1u << 20;
  u16*   h    = (u16*)(ws + 0);          // 8 MB (reused as y)
  u16*   q    = (u16*)(ws + 8  * MB);    // 8 MB
  u16*   k    = (u16*)(ws + 16 * MB);    // 8 MB
  u16*   v    = (u16*)(ws + 24 * MB);    // 8 MB
  u16*   o    = (u16*)(ws + 32 * MB);    // 8 MB
  u16*   r    = (u16*)(ws + 8  * MB);    // 32 MB, reuses q..o region (after attention done)
  float* ares = (float*)(ws + 40 * MB);  // 16 MB fp32
  u16*   wqb  = (u16*)(ws + 56 * MB);
  u16*   wkb  = (u16*)(ws + 58 * MB);
  u16*   wvb  = (u16*)(ws + 60 * MB);
  u16*   wob  = (u16*)(ws + 62 * MB);
  u16*   w1b  = (u16*)(ws + 64 * MB);    // 8 MB
  u16*   w2b  = (u16*)(ws + 72 * MB);    // 8 MB
  float* stats= (float*)(ws + 80 * MB);  // 8 floats
  u16*   y    = h;

  (void)hipMemsetAsync(stats, 0, 64, stream);

  // weights -> bf16
  cvt_kernel<<<512,  256, 0, stream>>>(wq, wqb, DIM * DIM);
  cvt_kernel<<<512,  256, 0, stream>>>(wk, wkb, DIM * DIM);
  cvt_kernel<<<512,  256, 0, stream>>>(wv, wvb, DIM * DIM);
  cvt_kernel<<<512,  256, 0, stream>>>(wo, wob, DIM * DIM);
  cvt_kernel<<<2048, 256, 0, stream>>>(w1, w1b, FFD * DIM);
  cvt_kernel<<<2048, 256, 0, stream>>>(w2, w2b, DIM * FFD);

  // LN1
  reduce_stats_kernel<<<dim3(64, 2), 256, 0, stream>>>(x, stats);
  ln_apply_kernel<<<4096, 256, 0, stream>>>(x, stats, h);

  // QKV
  gemm_qkv_kernel<<<dim3(8, 32, 3), 256, 0, stream>>>(h, wqb, wkb, wvb, bq, bk, bv, q, k, v);

  // attention
  attn_kernel<<<dim3(16, 16, 2), 256, 0, stream>>>(q, k, v, o);

  // out-proj + residual(x) -> ares (fp32)
  gemm_bt_kernel<0, 1, 0><<<dim3(8, 32), 256, 0, stream>>>(o, wob, bo, x, ares, MROWS, DIM, DIM);

  // LN2
  reduce_stats_kernel<<<dim3(64, 2), 256, 0, stream>>>(ares, stats + 4);
  ln_apply_kernel<<<4096, 256, 0, stream>>>(ares, stats + 4, y);

  // FFN
  gemm_bt_kernel<1, 0, 1><<<dim3(32, 32), 256, 0, stream>>>(y, w1b, b1, nullptr, r, MROWS, FFD, DIM);
  gemm_bt_kernel<0, 1, 0><<<dim3(8, 32), 256, 0, stream>>>(r, w2b, b2, x, out, MROWS, DIM, FFD);
}